// Round 1
// baseline (49818.863 us; speedup 1.0000x reference)
//
#include <hip/hip_runtime.h>
#include <hip/hip_cooperative_groups.h>
#include <math.h>

namespace cg = cooperative_groups;

constexpr int T_ = 512, B_ = 128, D_ = 512, V_ = 33, E_ = 128;
constexpr int G4 = 4 * D_;          // 2048
constexpr int BD = B_ * D_;         // 65536
constexpr int BV = B_ * V_;         // 4224
constexpr int TWO_D = 2 * D_;       // 1024

// ---------------------------------------------------------------- prep
// g0[c] = b_ih[c] + b_hh[c] + sum_e b_emb[e]*W_ih[e,c]   (x is constant = b_emb)
// WoT[v][j] = W_out[j][v]  (transposed for coalesced per-v dots)
__global__ void prep_kernel(const float* __restrict__ b_emb, const float* __restrict__ W_ih,
                            const float* __restrict__ b_ih, const float* __restrict__ b_hh,
                            const float* __restrict__ W_out,
                            float* __restrict__ g0, float* __restrict__ WoT) {
    int idx = blockIdx.x * 256 + threadIdx.x;
    if (idx < G4) {
        float acc = b_ih[idx] + b_hh[idx];
        for (int e = 0; e < E_; ++e) acc = fmaf(b_emb[e], W_ih[e * G4 + idx], acc);
        g0[idx] = acc;
    } else {
        int k = idx - G4;
        if (k < V_ * TWO_D) {
            int v = k / TWO_D, j = k % TWO_D;
            WoT[v * TWO_D + j] = W_out[j * V_ + v];
        }
    }
}

// ---------------------------------------------------------------- rowsum (f64)
// rowsum[t*B+b] = sum_d enc[t,b,d]   (one wave per row)
__global__ void rowsum_kernel(const float* __restrict__ enc, double* __restrict__ rowsum) {
    int wave = threadIdx.x >> 6, lane = threadIdx.x & 63;
    int row = blockIdx.x * 4 + wave;
    const float* p = enc + (size_t)row * D_;
    double s = 0.0;
    #pragma unroll
    for (int k = 0; k < 8; ++k) s += (double)p[k * 64 + lane];
    for (int off = 32; off; off >>= 1) s += __shfl_down(s, off, 64);
    if (lane == 0) rowsum[row] = s;
}

// ---------------------------------------------------------------- lstm (cooperative)
// 512 blocks x 128 threads. Block = (row-group rg of 16 rows) x (col-group of 8 cols/gate).
// Thread owns one (b, c): computes all 4 gate dots, keeps c_cell in a register.
// H_{t-1} row tile staged in LDS; W_hh streamed from L2. One grid.sync per step.
__global__ void __launch_bounds__(128) lstm_kernel(const float* __restrict__ Whh,
                                                   const float* __restrict__ g0,
                                                   float* __restrict__ Hs) {
    __shared__ float tile[16][516];  // pad 516: conflict-free broadcast reads
    cg::grid_group grid = cg::this_grid();
    const int tid = threadIdx.x;
    const int rg  = blockIdx.x >> 6;   // 0..7
    const int cgp = blockIdx.x & 63;   // 0..63
    const int r   = tid >> 3;          // 0..15
    const int c8  = tid & 7;           // 0..7
    const int c   = cgp * 8 + c8;      // 0..511
    const int b   = rg * 16 + r;
    const float g0i = g0[c], g0f = g0[D_ + c], g0g = g0[2 * D_ + c], g0o = g0[3 * D_ + c];
    const float* __restrict__ Wc = Whh + c;
    float c_cell = 0.f;
    for (int t = 0; t < T_; ++t) {
        float ai = 0.f, af = 0.f, ag = 0.f, ao = 0.f;
        if (t > 0) {
            const float* src = Hs + (size_t)(t - 1) * BD + rg * 16 * D_;
            #pragma unroll
            for (int it = 0; it < 16; ++it) {
                float4 v = ((const float4*)(src + it * D_))[tid];
                *((float4*)&tile[it][tid * 4]) = v;
            }
            __syncthreads();
            #pragma unroll 4
            for (int d = 0; d < D_; ++d) {
                float h = tile[r][d];
                const float* wr = Wc + d * G4;
                ai = fmaf(h, wr[0],       ai);
                af = fmaf(h, wr[D_],      af);
                ag = fmaf(h, wr[2 * D_],  ag);
                ao = fmaf(h, wr[3 * D_],  ao);
            }
        }
        float gi = 1.f / (1.f + expf(-(ai + g0i)));
        float gf = 1.f / (1.f + expf(-(af + g0f)));
        float gg = tanhf(ag + g0g);
        float go = 1.f / (1.f + expf(-(ao + g0o)));
        c_cell = gf * c_cell + gi * gg;
        Hs[(size_t)t * BD + b * D_ + c] = go * tanhf(c_cell);
        grid.sync();
    }
}

// ---------------------------------------------------------------- score -> w  (parallel over t)
// block = (t, j-tile of 64). numer[j] = sum_i exp(score[i,j]); denom[j] (f64) via rowsum trick.
__global__ void score_kernel(const float* __restrict__ enc, const float* __restrict__ Hs,
                             const double* __restrict__ rowsum, float* __restrict__ wout) {
    __shared__ float Hj[B_][68];   // [b][jl], 64 j's, pad 68 (float4-aligned)
    __shared__ float Ei[B_][36];   // [b][il], 32 i's per tile
    __shared__ float numer[64];
    const int tid = threadIdx.x;
    const int t  = blockIdx.x >> 3;
    const int j0 = (blockIdx.x & 7) * 64;
    for (int i = 0; i < 32; ++i) {
        int idx = i * 256 + tid;
        int bb = idx >> 6, jl = idx & 63;
        Hj[bb][jl] = Hs[(size_t)t * BD + bb * D_ + j0 + jl];
    }
    if (tid < 64) numer[tid] = 0.f;
    __syncthreads();
    const int ti = tid & 15;   // i-pair group (contiguous 16-lane segments share tj)
    const int tj = tid >> 4;   // j-quad group
    for (int itile = 0; itile < 16; ++itile) {
        int i0 = itile * 32;
        for (int i = 0; i < 16; ++i) {
            int idx = i * 256 + tid;
            int bb = idx >> 5, il = idx & 31;
            Ei[bb][il] = enc[(size_t)t * BD + bb * D_ + i0 + il];
        }
        __syncthreads();
        float a00=0,a01=0,a02=0,a03=0,a10=0,a11=0,a12=0,a13=0;
        #pragma unroll 4
        for (int bb = 0; bb < B_; ++bb) {
            float2 e2 = *(const float2*)&Ei[bb][ti * 2];
            float4 h4 = *(const float4*)&Hj[bb][tj * 4];
            a00 = fmaf(e2.x, h4.x, a00); a01 = fmaf(e2.x, h4.y, a01);
            a02 = fmaf(e2.x, h4.z, a02); a03 = fmaf(e2.x, h4.w, a03);
            a10 = fmaf(e2.y, h4.x, a10); a11 = fmaf(e2.y, h4.y, a11);
            a12 = fmaf(e2.y, h4.z, a12); a13 = fmaf(e2.y, h4.w, a13);
        }
        float v0 = expf(a00) + expf(a10);
        float v1 = expf(a01) + expf(a11);
        float v2 = expf(a02) + expf(a12);
        float v3 = expf(a03) + expf(a13);
        #pragma unroll
        for (int off = 1; off < 16; off <<= 1) {
            v0 += __shfl_xor(v0, off, 16);
            v1 += __shfl_xor(v1, off, 16);
            v2 += __shfl_xor(v2, off, 16);
            v3 += __shfl_xor(v3, off, 16);
        }
        if (ti == 0) {
            numer[tj * 4 + 0] += v0;
            numer[tj * 4 + 1] += v1;
            numer[tj * 4 + 2] += v2;
            numer[tj * 4 + 3] += v3;
        }
        __syncthreads();
    }
    if (tid < 64) {
        const double* rs = rowsum + t * B_;
        double dd = 0.0;
        for (int bb = 0; bb < B_; ++bb) dd += rs[bb] * (double)Hj[bb][tid];
        wout[t * D_ + j0 + tid] = (float)((double)numer[tid] / dd);
    }
}

// ---------------------------------------------------------------- u & hlog (parallel over t,b)
// u[t,b,v]    = sum_j (w_t[j]*E_t[b,j]) * WoT[v][D+j]   (attn logit increment)
// hlog[t,b,v] = sum_j H_t[b,j] * WoT[v][j]
__global__ void ufuse_kernel(const float* __restrict__ enc, const float* __restrict__ Hs,
                             const float* __restrict__ wbuf, const float* __restrict__ WoT,
                             float* __restrict__ u, float* __restrict__ hlog) {
    int wave = threadIdx.x >> 6, lane = threadIdx.x & 63;
    int row = blockIdx.x * 4 + wave;        // row = t*B + b
    int t = row >> 7, b = row & 127;
    const float* Erow = enc + (size_t)row * D_;
    const float* Hrow = Hs  + (size_t)row * D_;
    const float* wrow = wbuf + t * D_;
    float ar[8], hr[8];
    #pragma unroll
    for (int k = 0; k < 8; ++k) {
        int j = k * 64 + lane;
        ar[k] = wrow[j] * Erow[j];
        hr[k] = Hrow[j];
    }
    for (int v = 0; v < V_; ++v) {
        const float* wo = WoT + v * TWO_D;
        float su = 0.f, sh = 0.f;
        #pragma unroll
        for (int k = 0; k < 8; ++k) {
            int j = k * 64 + lane;
            su = fmaf(ar[k], wo[D_ + j], su);
            sh = fmaf(hr[k], wo[j], sh);
        }
        for (int off = 32; off; off >>= 1) {
            su += __shfl_down(su, off, 64);
            sh += __shfl_down(sh, off, 64);
        }
        if (lane == 0) {
            u[(size_t)t * BV + b * V_ + v] = su;
            hlog[(size_t)row * V_ + v] = sh;
        }
    }
}

// ---------------------------------------------------------------- cumsum over t (in place)
__global__ void cumsum_kernel(float* __restrict__ u) {
    int bv = blockIdx.x * 256 + threadIdx.x;
    if (bv >= BV) return;
    float acc = 0.f;
    for (int t = 0; t < T_; ++t) {
        acc += u[(size_t)t * BV + bv];
        u[(size_t)t * BV + bv] = acc;
    }
}

// ---------------------------------------------------------------- log_softmax
__global__ void final_kernel(const float* __restrict__ hlog, const float* __restrict__ u,
                             const float* __restrict__ b_out, float* __restrict__ out) {
    int row = blockIdx.x * 256 + threadIdx.x;   // 65536 rows
    float logit[V_];
    float m = -INFINITY;
    #pragma unroll
    for (int v = 0; v < V_; ++v) {
        float x = hlog[(size_t)row * V_ + v] + u[(size_t)row * V_ + v] + b_out[v];
        logit[v] = x;
        m = fmaxf(m, x);
    }
    float s = 0.f;
    #pragma unroll
    for (int v = 0; v < V_; ++v) s += expf(logit[v] - m);
    float lse = m + logf(s);
    #pragma unroll
    for (int v = 0; v < V_; ++v) out[(size_t)row * V_ + v] = logit[v] - lse;
}

// ---------------------------------------------------------------- launch
extern "C" void kernel_launch(void* const* d_in, const int* in_sizes, int n_in,
                              void* d_out, int out_size, void* d_ws, size_t ws_size,
                              hipStream_t stream) {
    const float* enc   = (const float*)d_in[0];
    const float* b_emb = (const float*)d_in[2];
    const float* W_ih  = (const float*)d_in[3];
    const float* W_hh  = (const float*)d_in[4];
    const float* b_ih  = (const float*)d_in[5];
    const float* b_hh  = (const float*)d_in[6];
    const float* W_out = (const float*)d_in[7];
    const float* b_out = (const float*)d_in[8];
    float* out = (float*)d_out;

    char* p = (char*)d_ws;
    double* rowsum = (double*)p;              p += sizeof(double) * (size_t)T_ * B_;
    float* Hs      = (float*)p;               p += sizeof(float) * (size_t)T_ * BD;
    float* wbuf    = (float*)p;               p += sizeof(float) * (size_t)T_ * D_;
    float* u       = (float*)p;               p += sizeof(float) * (size_t)T_ * BV;
    float* hlog    = (float*)p;               p += sizeof(float) * (size_t)T_ * BV;
    float* g0      = (float*)p;               p += sizeof(float) * G4;
    float* WoT     = (float*)p;               p += sizeof(float) * V_ * TWO_D;

    prep_kernel<<<(G4 + V_ * TWO_D + 255) / 256, 256, 0, stream>>>(b_emb, W_ih, b_ih, b_hh, W_out, g0, WoT);
    rowsum_kernel<<<T_ * B_ / 4, 256, 0, stream>>>(enc, rowsum);
    {
        const float* Whh_p = W_hh;
        const float* g0_p  = g0;
        float* Hs_p = Hs;
        void* args[] = { (void*)&Whh_p, (void*)&g0_p, (void*)&Hs_p };
        hipLaunchCooperativeKernel(lstm_kernel, dim3(512), dim3(128), args, 0, stream);
    }
    score_kernel<<<T_ * 8, 256, 0, stream>>>(enc, Hs, rowsum, wbuf);
    ufuse_kernel<<<T_ * B_ / 4, 256, 0, stream>>>(enc, Hs, wbuf, WoT, u, hlog);
    cumsum_kernel<<<(BV + 255) / 256, 256, 0, stream>>>(u);
    final_kernel<<<T_ * B_ / 256, 256, 0, stream>>>(hlog, u, b_out, out);
}

// Round 2
// 33535.825 us; speedup vs baseline: 1.4855x; 1.4855x over previous
//
#include <hip/hip_runtime.h>
#include <hip/hip_cooperative_groups.h>
#include <math.h>

namespace cg = cooperative_groups;

constexpr int T_ = 512, B_ = 128, D_ = 512, V_ = 33, E_ = 128;
constexpr int G4 = 4 * D_;          // 2048
constexpr int BD = B_ * D_;         // 65536
constexpr int BV = B_ * V_;         // 4224
constexpr int TWO_D = 2 * D_;       // 1024

// ---------------------------------------------------------------- prep
__global__ void prep_kernel(const float* __restrict__ b_emb, const float* __restrict__ W_ih,
                            const float* __restrict__ b_ih, const float* __restrict__ b_hh,
                            const float* __restrict__ W_out,
                            float* __restrict__ g0, float* __restrict__ WoT) {
    int idx = blockIdx.x * 256 + threadIdx.x;
    if (idx < G4) {
        float acc = b_ih[idx] + b_hh[idx];
        for (int e = 0; e < E_; ++e) acc = fmaf(b_emb[e], W_ih[e * G4 + idx], acc);
        g0[idx] = acc;
    } else {
        int k = idx - G4;
        if (k < V_ * TWO_D) {
            int v = k / TWO_D, j = k % TWO_D;
            WoT[v * TWO_D + j] = W_out[j * V_ + v];
        }
    }
}

// ---------------------------------------------------------------- rowsum (f64)
__global__ void rowsum_kernel(const float* __restrict__ enc, double* __restrict__ rowsum) {
    int wave = threadIdx.x >> 6, lane = threadIdx.x & 63;
    int row = blockIdx.x * 4 + wave;
    const float* p = enc + (size_t)row * D_;
    double s = 0.0;
    #pragma unroll
    for (int k = 0; k < 8; ++k) s += (double)p[k * 64 + lane];
    for (int off = 32; off; off >>= 1) s += __shfl_down(s, off, 64);
    if (lane == 0) rowsum[row] = s;
}

// ---------------------------------------------------------------- lstm (cooperative)
// 512 blocks x 256 threads, 2 blocks/CU (64KB LDS each).
// Block (rg, cgp): rows rg*16..+15, gate-cols {g*512 + cgp*8 + c8}.
// W_hh columns staged to LDS ONCE (Wlds[d][g*8+c8]); inner loop is LDS+L1 only.
// Thread: c8 = tid&7, dh = (tid>>3)&1 (d-half), r = tid>>4.
// Each thread dots its d-half; __shfl_xor(...,8) combines halves (both lanes get
// the full sum and redundantly carry c_cell; dh==0 lanes store).
__global__ void __launch_bounds__(256) lstm_kernel(const float* __restrict__ Whh,
                                                   const float* __restrict__ g0,
                                                   float* __restrict__ Hs) {
    __shared__ float Wlds[512 * 32];   // 64 KB: [d][g*8+c8]
    cg::grid_group grid = cg::this_grid();
    const int tid = threadIdx.x;
    const int rg  = blockIdx.x >> 6;   // 0..7
    const int cgp = blockIdx.x & 63;   // 0..63
    const int c8  = tid & 7;
    const int dh  = (tid >> 3) & 1;
    const int r   = tid >> 4;          // 0..15
    const int b   = rg * 16 + r;
    const int c   = cgp * 8 + c8;      // 0..511

    // stage W columns: Wlds[d*32 + g*8 + c8l] = Whh[d][g*512 + cgp*8 + c8l]
    for (int i = tid; i < 512 * 32; i += 256) {
        int d = i >> 5, col = i & 31;
        int g = col >> 3, c8l = col & 7;
        Wlds[i] = Whh[(size_t)d * G4 + g * D_ + cgp * 8 + c8l];
    }
    __syncthreads();

    const float g0i = g0[c], g0f = g0[D_ + c], g0g = g0[2 * D_ + c], g0o = g0[3 * D_ + c];
    float c_cell = 0.f;

    for (int t = 0; t < T_; ++t) {
        float ai = 0.f, af = 0.f, ag = 0.f, ao = 0.f;
        if (t > 0) {
            const float* hrow = Hs + (size_t)(t - 1) * BD + b * D_ + dh * 256;
            const float* wbase = Wlds + dh * 256 * 32 + c8;
            #pragma unroll 4
            for (int k = 0; k < 256; k += 4) {
                float4 h4 = *(const float4*)(hrow + k);
                #pragma unroll
                for (int q = 0; q < 4; ++q) {
                    float h = (&h4.x)[q];
                    const float* wr = wbase + (k + q) * 32;
                    ai = fmaf(h, wr[0],  ai);
                    af = fmaf(h, wr[8],  af);
                    ag = fmaf(h, wr[16], ag);
                    ao = fmaf(h, wr[24], ao);
                }
            }
            ai += __shfl_xor(ai, 8, 64);
            af += __shfl_xor(af, 8, 64);
            ag += __shfl_xor(ag, 8, 64);
            ao += __shfl_xor(ao, 8, 64);
        }
        float gi = 1.f / (1.f + expf(-(ai + g0i)));
        float gf = 1.f / (1.f + expf(-(af + g0f)));
        float gg = tanhf(ag + g0g);
        float go = 1.f / (1.f + expf(-(ao + g0o)));
        c_cell = gf * c_cell + gi * gg;
        float hnew = go * tanhf(c_cell);
        if (dh == 0) Hs[(size_t)t * BD + b * D_ + c] = hnew;
        grid.sync();
    }
}

// ---------------------------------------------------------------- score -> w  (parallel over t)
__global__ void score_kernel(const float* __restrict__ enc, const float* __restrict__ Hs,
                             const double* __restrict__ rowsum, float* __restrict__ wout) {
    __shared__ float Hj[B_][68];
    __shared__ float Ei[B_][36];
    __shared__ float numer[64];
    const int tid = threadIdx.x;
    const int t  = blockIdx.x >> 3;
    const int j0 = (blockIdx.x & 7) * 64;
    for (int i = 0; i < 32; ++i) {
        int idx = i * 256 + tid;
        int bb = idx >> 6, jl = idx & 63;
        Hj[bb][jl] = Hs[(size_t)t * BD + bb * D_ + j0 + jl];
    }
    if (tid < 64) numer[tid] = 0.f;
    __syncthreads();
    const int ti = tid & 15;
    const int tj = tid >> 4;
    for (int itile = 0; itile < 16; ++itile) {
        int i0 = itile * 32;
        for (int i = 0; i < 16; ++i) {
            int idx = i * 256 + tid;
            int bb = idx >> 5, il = idx & 31;
            Ei[bb][il] = enc[(size_t)t * BD + bb * D_ + i0 + il];
        }
        __syncthreads();
        float a00=0,a01=0,a02=0,a03=0,a10=0,a11=0,a12=0,a13=0;
        #pragma unroll 4
        for (int bb = 0; bb < B_; ++bb) {
            float2 e2 = *(const float2*)&Ei[bb][ti * 2];
            float4 h4 = *(const float4*)&Hj[bb][tj * 4];
            a00 = fmaf(e2.x, h4.x, a00); a01 = fmaf(e2.x, h4.y, a01);
            a02 = fmaf(e2.x, h4.z, a02); a03 = fmaf(e2.x, h4.w, a03);
            a10 = fmaf(e2.y, h4.x, a10); a11 = fmaf(e2.y, h4.y, a11);
            a12 = fmaf(e2.y, h4.z, a12); a13 = fmaf(e2.y, h4.w, a13);
        }
        float v0 = expf(a00) + expf(a10);
        float v1 = expf(a01) + expf(a11);
        float v2 = expf(a02) + expf(a12);
        float v3 = expf(a03) + expf(a13);
        #pragma unroll
        for (int off = 1; off < 16; off <<= 1) {
            v0 += __shfl_xor(v0, off, 16);
            v1 += __shfl_xor(v1, off, 16);
            v2 += __shfl_xor(v2, off, 16);
            v3 += __shfl_xor(v3, off, 16);
        }
        if (ti == 0) {
            numer[tj * 4 + 0] += v0;
            numer[tj * 4 + 1] += v1;
            numer[tj * 4 + 2] += v2;
            numer[tj * 4 + 3] += v3;
        }
        __syncthreads();
    }
    if (tid < 64) {
        const double* rs = rowsum + t * B_;
        double dd = 0.0;
        for (int bb = 0; bb < B_; ++bb) dd += rs[bb] * (double)Hj[bb][tid];
        wout[t * D_ + j0 + tid] = (float)((double)numer[tid] / dd);
    }
}

// ---------------------------------------------------------------- u & hlog (parallel over t,b)
__global__ void ufuse_kernel(const float* __restrict__ enc, const float* __restrict__ Hs,
                             const float* __restrict__ wbuf, const float* __restrict__ WoT,
                             float* __restrict__ u, float* __restrict__ hlog) {
    int wave = threadIdx.x >> 6, lane = threadIdx.x & 63;
    int row = blockIdx.x * 4 + wave;        // row = t*B + b
    int t = row >> 7, b = row & 127;
    const float* Erow = enc + (size_t)row * D_;
    const float* Hrow = Hs  + (size_t)row * D_;
    const float* wrow = wbuf + t * D_;
    float ar[8], hr[8];
    #pragma unroll
    for (int k = 0; k < 8; ++k) {
        int j = k * 64 + lane;
        ar[k] = wrow[j] * Erow[j];
        hr[k] = Hrow[j];
    }
    for (int v = 0; v < V_; ++v) {
        const float* wo = WoT + v * TWO_D;
        float su = 0.f, sh = 0.f;
        #pragma unroll
        for (int k = 0; k < 8; ++k) {
            int j = k * 64 + lane;
            su = fmaf(ar[k], wo[D_ + j], su);
            sh = fmaf(hr[k], wo[j], sh);
        }
        for (int off = 32; off; off >>= 1) {
            su += __shfl_down(su, off, 64);
            sh += __shfl_down(sh, off, 64);
        }
        if (lane == 0) {
            u[(size_t)t * BV + b * V_ + v] = su;
            hlog[(size_t)row * V_ + v] = sh;
        }
    }
}

// ---------------------------------------------------------------- cumsum over t (in place)
__global__ void cumsum_kernel(float* __restrict__ u) {
    int bv = blockIdx.x * 256 + threadIdx.x;
    if (bv >= BV) return;
    float acc = 0.f;
    for (int t = 0; t < T_; ++t) {
        acc += u[(size_t)t * BV + bv];
        u[(size_t)t * BV + bv] = acc;
    }
}

// ---------------------------------------------------------------- log_softmax
__global__ void final_kernel(const float* __restrict__ hlog, const float* __restrict__ u,
                             const float* __restrict__ b_out, float* __restrict__ out) {
    int row = blockIdx.x * 256 + threadIdx.x;   // 65536 rows
    float logit[V_];
    float m = -INFINITY;
    #pragma unroll
    for (int v = 0; v < V_; ++v) {
        float x = hlog[(size_t)row * V_ + v] + u[(size_t)row * V_ + v] + b_out[v];
        logit[v] = x;
        m = fmaxf(m, x);
    }
    float s = 0.f;
    #pragma unroll
    for (int v = 0; v < V_; ++v) s += expf(logit[v] - m);
    float lse = m + logf(s);
    #pragma unroll
    for (int v = 0; v < V_; ++v) out[(size_t)row * V_ + v] = logit[v] - lse;
}

// ---------------------------------------------------------------- launch
extern "C" void kernel_launch(void* const* d_in, const int* in_sizes, int n_in,
                              void* d_out, int out_size, void* d_ws, size_t ws_size,
                              hipStream_t stream) {
    const float* enc   = (const float*)d_in[0];
    const float* b_emb = (const float*)d_in[2];
    const float* W_ih  = (const float*)d_in[3];
    const float* W_hh  = (const float*)d_in[4];
    const float* b_ih  = (const float*)d_in[5];
    const float* b_hh  = (const float*)d_in[6];
    const float* W_out = (const float*)d_in[7];
    const float* b_out = (const float*)d_in[8];
    float* out = (float*)d_out;

    char* p = (char*)d_ws;
    double* rowsum = (double*)p;              p += sizeof(double) * (size_t)T_ * B_;
    float* Hs      = (float*)p;               p += sizeof(float) * (size_t)T_ * BD;
    float* wbuf    = (float*)p;               p += sizeof(float) * (size_t)T_ * D_;
    float* u       = (float*)p;               p += sizeof(float) * (size_t)T_ * BV;
    float* hlog    = (float*)p;               p += sizeof(float) * (size_t)T_ * BV;
    float* g0      = (float*)p;               p += sizeof(float) * G4;
    float* WoT     = (float*)p;               p += sizeof(float) * V_ * TWO_D;

    prep_kernel<<<(G4 + V_ * TWO_D + 255) / 256, 256, 0, stream>>>(b_emb, W_ih, b_ih, b_hh, W_out, g0, WoT);
    rowsum_kernel<<<T_ * B_ / 4, 256, 0, stream>>>(enc, rowsum);
    {
        const float* Whh_p = W_hh;
        const float* g0_p  = g0;
        float* Hs_p = Hs;
        void* args[] = { (void*)&Whh_p, (void*)&g0_p, (void*)&Hs_p };
        hipLaunchCooperativeKernel(lstm_kernel, dim3(512), dim3(256), args, 0, stream);
    }
    score_kernel<<<T_ * 8, 256, 0, stream>>>(enc, Hs, rowsum, wbuf);
    ufuse_kernel<<<T_ * B_ / 4, 256, 0, stream>>>(enc, Hs, wbuf, WoT, u, hlog);
    cumsum_kernel<<<(BV + 255) / 256, 256, 0, stream>>>(u);
    final_kernel<<<T_ * B_ / 256, 256, 0, stream>>>(hlog, u, b_out, out);
}

// Round 3
// 19988.307 us; speedup vs baseline: 2.4924x; 1.6778x over previous
//
#include <hip/hip_runtime.h>
#include <hip/hip_cooperative_groups.h>
#include <math.h>

namespace cg = cooperative_groups;

constexpr int T_ = 512, B_ = 128, D_ = 512, V_ = 33, E_ = 128;
constexpr int G4 = 4 * D_;          // 2048
constexpr int BD = B_ * D_;         // 65536
constexpr int BV = B_ * V_;         // 4224
constexpr int TWO_D = 2 * D_;       // 1024
constexpr int WIMG_HALF = 1048576;  // shorts per (hi|lo) plane of W image

typedef __attribute__((ext_vector_type(8))) short short8;
typedef __attribute__((ext_vector_type(4))) float floatx4;

__device__ inline short f2bf(float f) {
    unsigned u = __float_as_uint(f);
    unsigned r = (u + 0x7fff + ((u >> 16) & 1)) >> 16;
    return (short)r;
}
__device__ inline float bf2f(short s) {
    return __uint_as_float(((unsigned)(unsigned short)s) << 16);
}

// ---------------------------------------------------------------- prep
// g0[c] = b_ih[c] + b_hh[c] + sum_e b_emb[e]*W_ih[e,c];  WoT[v][j] = W_out[j][v]
__global__ void prep_kernel(const float* __restrict__ b_emb, const float* __restrict__ W_ih,
                            const float* __restrict__ b_ih, const float* __restrict__ b_hh,
                            const float* __restrict__ W_out,
                            float* __restrict__ g0, float* __restrict__ WoT) {
    int idx = blockIdx.x * 256 + threadIdx.x;
    if (idx < G4) {
        float acc = b_ih[idx] + b_hh[idx];
        for (int e = 0; e < E_; ++e) acc = fmaf(b_emb[e], W_ih[e * G4 + idx], acc);
        g0[idx] = acc;
    } else {
        int k = idx - G4;
        if (k < V_ * TWO_D) {
            int v = k / TWO_D, j = k % TWO_D;
            WoT[v * TWO_D + j] = W_out[j * V_ + v];
        }
    }
}

// ---------------------------------------------------------------- prep2: W fragment image
// For block-n, gate g, ktile kt, lane l, elem j:
//   Wimg[(((n*4+g)*16+kt)*64+l)*8+j] = bf16_hi(W_hh[k][G]), lo at +WIMG_HALF
// where G = g*512 + n*16 + (l&15), k = kt*32 + (l>>4)*8 + j.
__global__ void prep2_kernel(const float* __restrict__ Whh, short* __restrict__ Wimg) {
    int idx = blockIdx.x * 256 + threadIdx.x;   // 2048*512 total
    int G = idx & 2047, k = idx >> 11;
    float v = Whh[(size_t)k * G4 + G];
    short hi = f2bf(v);
    short lo = f2bf(v - bf2f(hi));
    int g = G >> 9, cc = G & 511, n = cc >> 4, c = cc & 15;
    int kt = k >> 5, kg = (k >> 3) & 3, j = k & 7;
    int lane = kg * 16 + c;
    size_t dst = ((size_t)((n * 4 + g) * 16 + kt) * 64 + lane) * 8 + j;
    Wimg[dst] = hi;
    Wimg[dst + WIMG_HALF] = lo;
}

// ---------------------------------------------------------------- rowsum (f64)
__global__ void rowsum_kernel(const float* __restrict__ enc, double* __restrict__ rowsum) {
    int wave = threadIdx.x >> 6, lane = threadIdx.x & 63;
    int row = blockIdx.x * 4 + wave;
    const float* p = enc + (size_t)row * D_;
    double s = 0.0;
    #pragma unroll
    for (int k = 0; k < 8; ++k) s += (double)p[k * 64 + lane];
    for (int off = 32; off; off >>= 1) s += __shfl_down(s, off, 64);
    if (lane == 0) rowsum[row] = s;
}

// ---------------------------------------------------------------- lstm (cooperative, MFMA bf16x3)
// 256 blocks x 256 threads (1/CU). Block (m = blk>>5, n = blk&31): rows 16m..,
// D-cols 16n.. . Wave g in {i,f,g,o} computes gate g's 16x16 preact tile via
// mfma_f32_16x16x32_bf16, K=512 in 16 ktiles x 3 MFMA (hi*hi + hi*lo + lo*hi).
// A-frags from global bf16 ping-pong hb[2][hi|lo][128][512]; B-frags from the
// pre-swizzled Wimg (L2-resident). Gate-combine via 3KB LDS; c_cell lives in
// wave-0 registers. grid.sync per step.
__global__ void __launch_bounds__(256) lstm_mfma(const short* __restrict__ Wimg,
                                                 const float* __restrict__ g0,
                                                 float* __restrict__ Hs,
                                                 short* __restrict__ hb) {
    __shared__ float xch[3][64][4];
    cg::grid_group grid = cg::this_grid();
    const int tid = threadIdx.x;
    const int l = tid & 63, g = tid >> 6;
    const int m = blockIdx.x >> 5, n = blockIdx.x & 31;
    const int col = l & 15, kg = l >> 4;
    const short* __restrict__ bbase = Wimg + ((size_t)((n * 4 + g) * 16) * 64 + l) * 8;
    const int arow = m * 16 + col;
    const float g0v = g0[g * 512 + n * 16 + col];
    float cc0 = 0.f, cc1 = 0.f, cc2 = 0.f, cc3 = 0.f;

    for (int t = 0; t < T_; ++t) {
        floatx4 acc = {0.f, 0.f, 0.f, 0.f};
        if (t > 0) {
            const short* __restrict__ ab = hb + (size_t)((t - 1) & 1) * 131072 + arow * 512 + kg * 8;
            #pragma unroll
            for (int kt = 0; kt < 16; ++kt) {
                short8 ahi = *(const short8*)(ab + kt * 32);
                short8 alo = *(const short8*)(ab + 65536 + kt * 32);
                short8 bhi = *(const short8*)(bbase + kt * 512);
                short8 blo = *(const short8*)(bbase + WIMG_HALF + kt * 512);
                acc = __builtin_amdgcn_mfma_f32_16x16x32_bf16(ahi, bhi, acc, 0, 0, 0);
                acc = __builtin_amdgcn_mfma_f32_16x16x32_bf16(ahi, blo, acc, 0, 0, 0);
                acc = __builtin_amdgcn_mfma_f32_16x16x32_bf16(alo, bhi, acc, 0, 0, 0);
            }
        }
        if (g > 0) {
            xch[g - 1][l][0] = acc[0] + g0v;
            xch[g - 1][l][1] = acc[1] + g0v;
            xch[g - 1][l][2] = acc[2] + g0v;
            xch[g - 1][l][3] = acc[3] + g0v;
        }
        __syncthreads();
        if (g == 0) {
            float ip[4], fp[4], gp[4], op[4];
            #pragma unroll
            for (int j = 0; j < 4; ++j) {
                ip[j] = acc[j] + g0v;
                fp[j] = xch[0][l][j];
                gp[j] = xch[1][l][j];
                op[j] = xch[2][l][j];
            }
            float* cc[4] = {&cc0, &cc1, &cc2, &cc3};
            short* hw = hb + (size_t)(t & 1) * 131072;
            #pragma unroll
            for (int j = 0; j < 4; ++j) {
                float i_ = 1.f / (1.f + expf(-ip[j]));
                float f_ = 1.f / (1.f + expf(-fp[j]));
                float gg = tanhf(gp[j]);
                float o_ = 1.f / (1.f + expf(-op[j]));
                float c_new = f_ * (*cc[j]) + i_ * gg;
                *cc[j] = c_new;
                float h = o_ * tanhf(c_new);
                int row = m * 16 + kg * 4 + j;
                int pos = row * 512 + n * 16 + col;
                Hs[(size_t)t * BD + pos] = h;
                short hi = f2bf(h);
                short lo = f2bf(h - bf2f(hi));
                hw[pos] = hi;
                hw[65536 + pos] = lo;
            }
        }
        grid.sync();
    }
}

// ---------------------------------------------------------------- score -> w  (parallel over t)
__global__ void score_kernel(const float* __restrict__ enc, const float* __restrict__ Hs,
                             const double* __restrict__ rowsum, float* __restrict__ wout) {
    __shared__ float Hj[B_][68];
    __shared__ float Ei[B_][36];
    __shared__ float numer[64];
    const int tid = threadIdx.x;
    const int t  = blockIdx.x >> 3;
    const int j0 = (blockIdx.x & 7) * 64;
    for (int i = 0; i < 32; ++i) {
        int idx = i * 256 + tid;
        int bb = idx >> 6, jl = idx & 63;
        Hj[bb][jl] = Hs[(size_t)t * BD + bb * D_ + j0 + jl];
    }
    if (tid < 64) numer[tid] = 0.f;
    __syncthreads();
    const int ti = tid & 15;
    const int tj = tid >> 4;
    for (int itile = 0; itile < 16; ++itile) {
        int i0 = itile * 32;
        for (int i = 0; i < 16; ++i) {
            int idx = i * 256 + tid;
            int bb = idx >> 5, il = idx & 31;
            Ei[bb][il] = enc[(size_t)t * BD + bb * D_ + i0 + il];
        }
        __syncthreads();
        float a00=0,a01=0,a02=0,a03=0,a10=0,a11=0,a12=0,a13=0;
        #pragma unroll 4
        for (int bb = 0; bb < B_; ++bb) {
            float2 e2 = *(const float2*)&Ei[bb][ti * 2];
            float4 h4 = *(const float4*)&Hj[bb][tj * 4];
            a00 = fmaf(e2.x, h4.x, a00); a01 = fmaf(e2.x, h4.y, a01);
            a02 = fmaf(e2.x, h4.z, a02); a03 = fmaf(e2.x, h4.w, a03);
            a10 = fmaf(e2.y, h4.x, a10); a11 = fmaf(e2.y, h4.y, a11);
            a12 = fmaf(e2.y, h4.z, a12); a13 = fmaf(e2.y, h4.w, a13);
        }
        float v0 = expf(a00) + expf(a10);
        float v1 = expf(a01) + expf(a11);
        float v2 = expf(a02) + expf(a12);
        float v3 = expf(a03) + expf(a13);
        #pragma unroll
        for (int off = 1; off < 16; off <<= 1) {
            v0 += __shfl_xor(v0, off, 16);
            v1 += __shfl_xor(v1, off, 16);
            v2 += __shfl_xor(v2, off, 16);
            v3 += __shfl_xor(v3, off, 16);
        }
        if (ti == 0) {
            numer[tj * 4 + 0] += v0;
            numer[tj * 4 + 1] += v1;
            numer[tj * 4 + 2] += v2;
            numer[tj * 4 + 3] += v3;
        }
        __syncthreads();
    }
    if (tid < 64) {
        const double* rs = rowsum + t * B_;
        double dd = 0.0;
        for (int bb = 0; bb < B_; ++bb) dd += rs[bb] * (double)Hj[bb][tid];
        wout[t * D_ + j0 + tid] = (float)((double)numer[tid] / dd);
    }
}

// ---------------------------------------------------------------- u & hlog (parallel over t,b)
__global__ void ufuse_kernel(const float* __restrict__ enc, const float* __restrict__ Hs,
                             const float* __restrict__ wbuf, const float* __restrict__ WoT,
                             float* __restrict__ u, float* __restrict__ hlog) {
    int wave = threadIdx.x >> 6, lane = threadIdx.x & 63;
    int row = blockIdx.x * 4 + wave;        // row = t*B + b
    int t = row >> 7, b = row & 127;
    const float* Erow = enc + (size_t)row * D_;
    const float* Hrow = Hs  + (size_t)row * D_;
    const float* wrow = wbuf + t * D_;
    float ar[8], hr[8];
    #pragma unroll
    for (int k = 0; k < 8; ++k) {
        int j = k * 64 + lane;
        ar[k] = wrow[j] * Erow[j];
        hr[k] = Hrow[j];
    }
    for (int v = 0; v < V_; ++v) {
        const float* wo = WoT + v * TWO_D;
        float su = 0.f, sh = 0.f;
        #pragma unroll
        for (int k = 0; k < 8; ++k) {
            int j = k * 64 + lane;
            su = fmaf(ar[k], wo[D_ + j], su);
            sh = fmaf(hr[k], wo[j], sh);
        }
        for (int off = 32; off; off >>= 1) {
            su += __shfl_down(su, off, 64);
            sh += __shfl_down(sh, off, 64);
        }
        if (lane == 0) {
            u[(size_t)t * BV + b * V_ + v] = su;
            hlog[(size_t)row * V_ + v] = sh;
        }
    }
}

// ---------------------------------------------------------------- cumsum over t (in place)
__global__ void cumsum_kernel(float* __restrict__ u) {
    int bv = blockIdx.x * 256 + threadIdx.x;
    if (bv >= BV) return;
    float acc = 0.f;
    for (int t = 0; t < T_; ++t) {
        acc += u[(size_t)t * BV + bv];
        u[(size_t)t * BV + bv] = acc;
    }
}

// ---------------------------------------------------------------- log_softmax
__global__ void final_kernel(const float* __restrict__ hlog, const float* __restrict__ u,
                             const float* __restrict__ b_out, float* __restrict__ out) {
    int row = blockIdx.x * 256 + threadIdx.x;   // 65536 rows
    float logit[V_];
    float m = -INFINITY;
    #pragma unroll
    for (int v = 0; v < V_; ++v) {
        float x = hlog[(size_t)row * V_ + v] + u[(size_t)row * V_ + v] + b_out[v];
        logit[v] = x;
        m = fmaxf(m, x);
    }
    float s = 0.f;
    #pragma unroll
    for (int v = 0; v < V_; ++v) s += expf(logit[v] - m);
    float lse = m + logf(s);
    #pragma unroll
    for (int v = 0; v < V_; ++v) out[(size_t)row * V_ + v] = logit[v] - lse;
}

// ---------------------------------------------------------------- launch
extern "C" void kernel_launch(void* const* d_in, const int* in_sizes, int n_in,
                              void* d_out, int out_size, void* d_ws, size_t ws_size,
                              hipStream_t stream) {
    const float* enc   = (const float*)d_in[0];
    const float* b_emb = (const float*)d_in[2];
    const float* W_ih  = (const float*)d_in[3];
    const float* W_hh  = (const float*)d_in[4];
    const float* b_ih  = (const float*)d_in[5];
    const float* b_hh  = (const float*)d_in[6];
    const float* W_out = (const float*)d_in[7];
    const float* b_out = (const float*)d_in[8];
    float* out = (float*)d_out;

    char* p = (char*)d_ws;
    double* rowsum = (double*)p;              p += sizeof(double) * (size_t)T_ * B_;
    float* Hs      = (float*)p;               p += sizeof(float) * (size_t)T_ * BD;
    float* wbuf    = (float*)p;               p += sizeof(float) * (size_t)T_ * D_;
    float* u       = (float*)p;               p += sizeof(float) * (size_t)T_ * BV;
    float* hlog    = (float*)p;               p += sizeof(float) * (size_t)T_ * BV;
    float* g0      = (float*)p;               p += sizeof(float) * G4;
    float* WoT     = (float*)p;               p += sizeof(float) * V_ * TWO_D;
    short* Wimg    = (short*)p;               p += sizeof(short) * 2 * WIMG_HALF;
    short* hb      = (short*)p;               p += sizeof(short) * 2 * 2 * BD;

    prep_kernel<<<(G4 + V_ * TWO_D + 255) / 256, 256, 0, stream>>>(b_emb, W_ih, b_ih, b_hh, W_out, g0, WoT);
    prep2_kernel<<<(G4 * D_) / 256, 256, 0, stream>>>(W_hh, Wimg);
    rowsum_kernel<<<T_ * B_ / 4, 256, 0, stream>>>(enc, rowsum);
    {
        const short* Wimg_p = Wimg;
        const float* g0_p   = g0;
        float* Hs_p = Hs;
        short* hb_p = hb;
        void* args[] = { (void*)&Wimg_p, (void*)&g0_p, (void*)&Hs_p, (void*)&hb_p };
        hipLaunchCooperativeKernel(lstm_mfma, dim3(256), dim3(256), args, 0, stream);
    }
    score_kernel<<<T_ * 8, 256, 0, stream>>>(enc, Hs, rowsum, wbuf);
    ufuse_kernel<<<T_ * B_ / 4, 256, 0, stream>>>(enc, Hs, wbuf, WoT, u, hlog);
    cumsum_kernel<<<(BV + 255) / 256, 256, 0, stream>>>(u);
    final_kernel<<<T_ * B_ / 256, 256, 0, stream>>>(hlog, u, b_out, out);
}

// Round 4
// 18331.502 us; speedup vs baseline: 2.7177x; 1.0904x over previous
//
#include <hip/hip_runtime.h>
#include <hip/hip_cooperative_groups.h>
#include <math.h>

namespace cg = cooperative_groups;

constexpr int T_ = 512, B_ = 128, D_ = 512, V_ = 33, E_ = 128;
constexpr int G4 = 4 * D_;          // 2048
constexpr int BD = B_ * D_;         // 65536
constexpr int BV = B_ * V_;         // 4224
constexpr int TWO_D = 2 * D_;       // 1024
constexpr int WIMG_HALF = 1048576;  // shorts per (hi|lo) plane of W image

typedef __attribute__((ext_vector_type(8))) short short8;
typedef __attribute__((ext_vector_type(4))) float floatx4;

__device__ inline short f2bf(float f) {
    unsigned u = __float_as_uint(f);
    unsigned r = (u + 0x7fff + ((u >> 16) & 1)) >> 16;
    return (short)r;
}
__device__ inline float bf2f(short s) {
    return __uint_as_float(((unsigned)(unsigned short)s) << 16);
}

// ---------------------------------------------------------------- prep
__global__ void prep_kernel(const float* __restrict__ b_emb, const float* __restrict__ W_ih,
                            const float* __restrict__ b_ih, const float* __restrict__ b_hh,
                            const float* __restrict__ W_out,
                            float* __restrict__ g0, float* __restrict__ WoT) {
    int idx = blockIdx.x * 256 + threadIdx.x;
    if (idx < G4) {
        float acc = b_ih[idx] + b_hh[idx];
        for (int e = 0; e < E_; ++e) acc = fmaf(b_emb[e], W_ih[e * G4 + idx], acc);
        g0[idx] = acc;
    } else {
        int k = idx - G4;
        if (k < V_ * TWO_D) {
            int v = k / TWO_D, j = k % TWO_D;
            WoT[v * TWO_D + j] = W_out[j * V_ + v];
        }
    }
}

// ---------------------------------------------------------------- prep2: W fragment image
__global__ void prep2_kernel(const float* __restrict__ Whh, short* __restrict__ Wimg) {
    int idx = blockIdx.x * 256 + threadIdx.x;   // 2048*512 total
    int G = idx & 2047, k = idx >> 11;
    float v = Whh[(size_t)k * G4 + G];
    short hi = f2bf(v);
    short lo = f2bf(v - bf2f(hi));
    int g = G >> 9, cc = G & 511, n = cc >> 4, c = cc & 15;
    int kt = k >> 5, kg = (k >> 3) & 3, j = k & 7;
    int lane = kg * 16 + c;
    size_t dst = ((size_t)((n * 4 + g) * 16 + kt) * 64 + lane) * 8 + j;
    Wimg[dst] = hi;
    Wimg[dst + WIMG_HALF] = lo;
}

// ---------------------------------------------------------------- rowsum (f64)
__global__ void rowsum_kernel(const float* __restrict__ enc, double* __restrict__ rowsum) {
    int wave = threadIdx.x >> 6, lane = threadIdx.x & 63;
    int row = blockIdx.x * 4 + wave;
    const float* p = enc + (size_t)row * D_;
    double s = 0.0;
    #pragma unroll
    for (int k = 0; k < 8; ++k) s += (double)p[k * 64 + lane];
    for (int off = 32; off; off >>= 1) s += __shfl_down(s, off, 64);
    if (lane == 0) rowsum[row] = s;
}

// ---------------------------------------------------------------- lstm (cooperative, MFMA bf16x3)
// 256 blocks x 256 threads (1/CU). Block: m = blk&7 (XCD-affine row group),
// n = blk>>3. Wave g computes gate g's 16x16 preact tile.
// B (W frags) hoisted to REGISTERS once (128 VGPRs). A frags fully prefetched
// per step into register arrays (32 parallel global loads) -> single latency
// exposure, then 48 register-only MFMAs. Epilogue math identical to R3.
__global__ void __launch_bounds__(256, 1) lstm_mfma(const short* __restrict__ Wimg,
                                                    const float* __restrict__ g0,
                                                    float* __restrict__ Hs,
                                                    short* __restrict__ hb) {
    __shared__ float xch[3][64][4];
    cg::grid_group grid = cg::this_grid();
    const int tid = threadIdx.x;
    const int l = tid & 63, g = tid >> 6;
    const int m = blockIdx.x & 7, n = blockIdx.x >> 3;
    const int col = l & 15, kg = l >> 4;
    const int arow = m * 16 + col;
    const float g0v = g0[g * 512 + n * 16 + col];

    // Hoist B fragments (this block/wave's W slice) into registers, once.
    const short* __restrict__ bbase = Wimg + ((size_t)((n * 4 + g) * 16) * 64 + l) * 8;
    short8 bhi[16], blo[16];
    #pragma unroll
    for (int kt = 0; kt < 16; ++kt) {
        bhi[kt] = *(const short8*)(bbase + kt * 512);
        blo[kt] = *(const short8*)(bbase + WIMG_HALF + kt * 512);
    }

    float cc0 = 0.f, cc1 = 0.f, cc2 = 0.f, cc3 = 0.f;

    for (int t = 0; t < T_; ++t) {
        floatx4 acc = {0.f, 0.f, 0.f, 0.f};
        if (t > 0) {
            const short* __restrict__ ab = hb + (size_t)((t - 1) & 1) * 131072 + arow * 512 + kg * 8;
            short8 ahi[16], alo[16];
            #pragma unroll
            for (int kt = 0; kt < 16; ++kt) {
                ahi[kt] = *(const short8*)(ab + kt * 32);
                alo[kt] = *(const short8*)(ab + 65536 + kt * 32);
            }
            #pragma unroll
            for (int kt = 0; kt < 16; ++kt) {
                acc = __builtin_amdgcn_mfma_f32_16x16x32_bf16(ahi[kt], bhi[kt], acc, 0, 0, 0);
                acc = __builtin_amdgcn_mfma_f32_16x16x32_bf16(ahi[kt], blo[kt], acc, 0, 0, 0);
                acc = __builtin_amdgcn_mfma_f32_16x16x32_bf16(alo[kt], bhi[kt], acc, 0, 0, 0);
            }
        }
        if (g > 0) {
            xch[g - 1][l][0] = acc[0] + g0v;
            xch[g - 1][l][1] = acc[1] + g0v;
            xch[g - 1][l][2] = acc[2] + g0v;
            xch[g - 1][l][3] = acc[3] + g0v;
        }
        __syncthreads();
        if (g == 0) {
            float ip[4], fp[4], gp[4], op[4];
            #pragma unroll
            for (int j = 0; j < 4; ++j) {
                ip[j] = acc[j] + g0v;
                fp[j] = xch[0][l][j];
                gp[j] = xch[1][l][j];
                op[j] = xch[2][l][j];
            }
            float* cc[4] = {&cc0, &cc1, &cc2, &cc3};
            short* hw = hb + (size_t)(t & 1) * 131072;
            #pragma unroll
            for (int j = 0; j < 4; ++j) {
                float i_ = 1.f / (1.f + expf(-ip[j]));
                float f_ = 1.f / (1.f + expf(-fp[j]));
                float gg = tanhf(gp[j]);
                float o_ = 1.f / (1.f + expf(-op[j]));
                float c_new = f_ * (*cc[j]) + i_ * gg;
                *cc[j] = c_new;
                float h = o_ * tanhf(c_new);
                int row = m * 16 + kg * 4 + j;
                int pos = row * 512 + n * 16 + col;
                Hs[(size_t)t * BD + pos] = h;
                short hi = f2bf(h);
                short lo = f2bf(h - bf2f(hi));
                hw[pos] = hi;
                hw[65536 + pos] = lo;
            }
        }
        grid.sync();
    }
}

// ---------------------------------------------------------------- score -> w  (parallel over t)
__global__ void score_kernel(const float* __restrict__ enc, const float* __restrict__ Hs,
                             const double* __restrict__ rowsum, float* __restrict__ wout) {
    __shared__ float Hj[B_][68];
    __shared__ float Ei[B_][36];
    __shared__ float numer[64];
    const int tid = threadIdx.x;
    const int t  = blockIdx.x >> 3;
    const int j0 = (blockIdx.x & 7) * 64;
    for (int i = 0; i < 32; ++i) {
        int idx = i * 256 + tid;
        int bb = idx >> 6, jl = idx & 63;
        Hj[bb][jl] = Hs[(size_t)t * BD + bb * D_ + j0 + jl];
    }
    if (tid < 64) numer[tid] = 0.f;
    __syncthreads();
    const int ti = tid & 15;
    const int tj = tid >> 4;
    for (int itile = 0; itile < 16; ++itile) {
        int i0 = itile * 32;
        for (int i = 0; i < 16; ++i) {
            int idx = i * 256 + tid;
            int bb = idx >> 5, il = idx & 31;
            Ei[bb][il] = enc[(size_t)t * BD + bb * D_ + i0 + il];
        }
        __syncthreads();
        float a00=0,a01=0,a02=0,a03=0,a10=0,a11=0,a12=0,a13=0;
        #pragma unroll 4
        for (int bb = 0; bb < B_; ++bb) {
            float2 e2 = *(const float2*)&Ei[bb][ti * 2];
            float4 h4 = *(const float4*)&Hj[bb][tj * 4];
            a00 = fmaf(e2.x, h4.x, a00); a01 = fmaf(e2.x, h4.y, a01);
            a02 = fmaf(e2.x, h4.z, a02); a03 = fmaf(e2.x, h4.w, a03);
            a10 = fmaf(e2.y, h4.x, a10); a11 = fmaf(e2.y, h4.y, a11);
            a12 = fmaf(e2.y, h4.z, a12); a13 = fmaf(e2.y, h4.w, a13);
        }
        float v0 = expf(a00) + expf(a10);
        float v1 = expf(a01) + expf(a11);
        float v2 = expf(a02) + expf(a12);
        float v3 = expf(a03) + expf(a13);
        #pragma unroll
        for (int off = 1; off < 16; off <<= 1) {
            v0 += __shfl_xor(v0, off, 16);
            v1 += __shfl_xor(v1, off, 16);
            v2 += __shfl_xor(v2, off, 16);
            v3 += __shfl_xor(v3, off, 16);
        }
        if (ti == 0) {
            numer[tj * 4 + 0] += v0;
            numer[tj * 4 + 1] += v1;
            numer[tj * 4 + 2] += v2;
            numer[tj * 4 + 3] += v3;
        }
        __syncthreads();
    }
    if (tid < 64) {
        const double* rs = rowsum + t * B_;
        double dd = 0.0;
        for (int bb = 0; bb < B_; ++bb) dd += rs[bb] * (double)Hj[bb][tid];
        wout[t * D_ + j0 + tid] = (float)((double)numer[tid] / dd);
    }
}

// ---------------------------------------------------------------- u & hlog (parallel over t,b)
__global__ void ufuse_kernel(const float* __restrict__ enc, const float* __restrict__ Hs,
                             const float* __restrict__ wbuf, const float* __restrict__ WoT,
                             float* __restrict__ u, float* __restrict__ hlog) {
    int wave = threadIdx.x >> 6, lane = threadIdx.x & 63;
    int row = blockIdx.x * 4 + wave;        // row = t*B + b
    int t = row >> 7, b = row & 127;
    const float* Erow = enc + (size_t)row * D_;
    const float* Hrow = Hs  + (size_t)row * D_;
    const float* wrow = wbuf + t * D_;
    float ar[8], hr[8];
    #pragma unroll
    for (int k = 0; k < 8; ++k) {
        int j = k * 64 + lane;
        ar[k] = wrow[j] * Erow[j];
        hr[k] = Hrow[j];
    }
    for (int v = 0; v < V_; ++v) {
        const float* wo = WoT + v * TWO_D;
        float su = 0.f, sh = 0.f;
        #pragma unroll
        for (int k = 0; k < 8; ++k) {
            int j = k * 64 + lane;
            su = fmaf(ar[k], wo[D_ + j], su);
            sh = fmaf(hr[k], wo[j], sh);
        }
        for (int off = 32; off; off >>= 1) {
            su += __shfl_down(su, off, 64);
            sh += __shfl_down(sh, off, 64);
        }
        if (lane == 0) {
            u[(size_t)t * BV + b * V_ + v] = su;
            hlog[(size_t)row * V_ + v] = sh;
        }
    }
}

// ---------------------------------------------------------------- cumsum over t (in place)
__global__ void cumsum_kernel(float* __restrict__ u) {
    int bv = blockIdx.x * 256 + threadIdx.x;
    if (bv >= BV) return;
    float acc = 0.f;
    for (int t = 0; t < T_; ++t) {
        acc += u[(size_t)t * BV + bv];
        u[(size_t)t * BV + bv] = acc;
    }
}

// ---------------------------------------------------------------- log_softmax
__global__ void final_kernel(const float* __restrict__ hlog, const float* __restrict__ u,
                             const float* __restrict__ b_out, float* __restrict__ out) {
    int row = blockIdx.x * 256 + threadIdx.x;   // 65536 rows
    float logit[V_];
    float m = -INFINITY;
    #pragma unroll
    for (int v = 0; v < V_; ++v) {
        float x = hlog[(size_t)row * V_ + v] + u[(size_t)row * V_ + v] + b_out[v];
        logit[v] = x;
        m = fmaxf(m, x);
    }
    float s = 0.f;
    #pragma unroll
    for (int v = 0; v < V_; ++v) s += expf(logit[v] - m);
    float lse = m + logf(s);
    #pragma unroll
    for (int v = 0; v < V_; ++v) out[(size_t)row * V_ + v] = logit[v] - lse;
}

// ---------------------------------------------------------------- launch
extern "C" void kernel_launch(void* const* d_in, const int* in_sizes, int n_in,
                              void* d_out, int out_size, void* d_ws, size_t ws_size,
                              hipStream_t stream) {
    const float* enc   = (const float*)d_in[0];
    const float* b_emb = (const float*)d_in[2];
    const float* W_ih  = (const float*)d_in[3];
    const float* W_hh  = (const float*)d_in[4];
    const float* b_ih  = (const float*)d_in[5];
    const float* b_hh  = (const float*)d_in[6];
    const float* W_out = (const float*)d_in[7];
    const float* b_out = (const float*)d_in[8];
    float* out = (float*)d_out;

    char* p = (char*)d_ws;
    double* rowsum = (double*)p;              p += sizeof(double) * (size_t)T_ * B_;
    float* Hs      = (float*)p;               p += sizeof(float) * (size_t)T_ * BD;
    float* wbuf    = (float*)p;               p += sizeof(float) * (size_t)T_ * D_;
    float* u       = (float*)p;               p += sizeof(float) * (size_t)T_ * BV;
    float* hlog    = (float*)p;               p += sizeof(float) * (size_t)T_ * BV;
    float* g0      = (float*)p;               p += sizeof(float) * G4;
    float* WoT     = (float*)p;               p += sizeof(float) * V_ * TWO_D;
    short* Wimg    = (short*)p;               p += sizeof(short) * 2 * WIMG_HALF;
    short* hb      = (short*)p;               p += sizeof(short) * 2 * 2 * BD;

    prep_kernel<<<(G4 + V_ * TWO_D + 255) / 256, 256, 0, stream>>>(b_emb, W_ih, b_ih, b_hh, W_out, g0, WoT);
    prep2_kernel<<<(G4 * D_) / 256, 256, 0, stream>>>(W_hh, Wimg);
    rowsum_kernel<<<T_ * B_ / 4, 256, 0, stream>>>(enc, rowsum);
    {
        const short* Wimg_p = Wimg;
        const float* g0_p   = g0;
        float* Hs_p = Hs;
        short* hb_p = hb;
        void* args[] = { (void*)&Wimg_p, (void*)&g0_p, (void*)&Hs_p, (void*)&hb_p };
        hipLaunchCooperativeKernel(lstm_mfma, dim3(256), dim3(256), args, 0, stream);
    }
    score_kernel<<<T_ * 8, 256, 0, stream>>>(enc, Hs, rowsum, wbuf);
    ufuse_kernel<<<T_ * B_ / 4, 256, 0, stream>>>(enc, Hs, wbuf, WoT, u, hlog);
    cumsum_kernel<<<(BV + 255) / 256, 256, 0, stream>>>(u);
    final_kernel<<<T_ * B_ / 256, 256, 0, stream>>>(hlog, u, b_out, out);
}